// Round 14
// baseline (374.838 us; speedup 1.0000x reference)
//
#include <hip/hip_runtime.h>

#define N_TOT 65536
#define DIM 256
#define KK 512
#define TT 4096
#define BB 16

typedef short bf16x8 __attribute__((ext_vector_type(8)));
typedef float f32x4 __attribute__((ext_vector_type(4)));

__device__ __forceinline__ ushort f2bf(float f) {
    unsigned u = __float_as_uint(f);
    unsigned r = (u + 0x7fffu + ((u >> 16) & 1u)) >> 16;
    return (ushort)r;
}

// ---------------- fused: se[k] + split emb -> eb[k][512] = [hi|lo] bf16 ----------------
__global__ void k_prep_e(const float* __restrict__ emb, float* __restrict__ se,
                         ushort* __restrict__ eb) {
    int k = blockIdx.x, tid = threadIdx.x;  // 64 threads
    int c0 = tid * 4;
    float4 v = *(const float4*)(emb + k * DIM + c0);
    float f[4] = {v.x, v.y, v.z, v.w};
    float s = f[0] * f[0] + f[1] * f[1] + f[2] * f[2] + f[3] * f[3];
#pragma unroll
    for (int m = 1; m < 64; m <<= 1) s += __shfl_xor(s, m);
    if (tid == 0) se[k] = s;
    ushort h[4], l[4];
#pragma unroll
    for (int j = 0; j < 4; ++j) {
        h[j] = f2bf(f[j]);
        float hf = __uint_as_float(((unsigned)h[j]) << 16);
        l[j] = f2bf(f[j] - hf);
    }
    uint2 hp = make_uint2((unsigned)h[0] | ((unsigned)h[1] << 16),
                          (unsigned)h[2] | ((unsigned)h[3] << 16));
    uint2 lp = make_uint2((unsigned)l[0] | ((unsigned)l[1] << 16),
                          (unsigned)l[2] | ((unsigned)l[3] << 16));
    *(uint2*)(eb + (size_t)k * 512 + c0) = hp;
    *(uint2*)(eb + (size_t)k * 512 + 256 + c0) = lp;
}

// ---------------- transpose + split x -> xt[n][512]; fused sum(x^2) -> lossA ----------------
__global__ __launch_bounds__(256) void k_split_x(const float* __restrict__ in,
                                                 ushort* __restrict__ xt,
                                                 double* __restrict__ lossA) {
    __shared__ float ls[64][65];
    __shared__ float r4[4];
    int tid = threadIdx.x;
    int b = blockIdx.x >> 8;
    int rest = blockIdx.x & 255;
    int tt = rest >> 2, dt = rest & 3;
    int t0 = tt * 64, d0 = dt * 64;
    int tl = tid & 63, dg = tid >> 6;
    const float* src = in + (size_t)b * DIM * TT + t0 + tl;
    float ssq = 0.f;
#pragma unroll
    for (int p = 0; p < 16; ++p) {
        int d = dg * 16 + p;
        float v = src[(size_t)(d0 + d) * TT];
        ls[d][tl] = v;
        ssq = fmaf(v, v, ssq);
    }
#pragma unroll
    for (int m = 1; m < 64; m <<= 1) ssq += __shfl_xor(ssq, m);
    if (tl == 0) r4[dg] = ssq;
    __syncthreads();
    int c0 = dg * 16;
    int n = b * TT + t0 + tl;
    ushort* row = xt + (size_t)n * 512;
    ushort h[16], l[16];
#pragma unroll
    for (int j = 0; j < 16; ++j) {
        float v = ls[c0 + j][tl];
        h[j] = f2bf(v);
        float hf = __uint_as_float(((unsigned)h[j]) << 16);
        l[j] = f2bf(v - hf);
    }
    uint hu[8], lu[8];
#pragma unroll
    for (int j = 0; j < 8; ++j) {
        hu[j] = (unsigned)h[2 * j] | ((unsigned)h[2 * j + 1] << 16);
        lu[j] = (unsigned)l[2 * j] | ((unsigned)l[2 * j + 1] << 16);
    }
    *(uint4*)(row + d0 + c0) = make_uint4(hu[0], hu[1], hu[2], hu[3]);
    *(uint4*)(row + d0 + c0 + 8) = make_uint4(hu[4], hu[5], hu[6], hu[7]);
    *(uint4*)(row + 256 + d0 + c0) = make_uint4(lu[0], lu[1], lu[2], lu[3]);
    *(uint4*)(row + 256 + d0 + c0 + 8) = make_uint4(lu[4], lu[5], lu[6], lu[7]);
    if (tid == 0) {
        double s = (double)r4[0] + (double)r4[1] + (double)r4[2] + (double)r4[3];
        atomicAdd(lossA, s);
    }
}

// ---------------- zero dw / counts / loss accumulators ----------------
__global__ void k_zero(float* __restrict__ dw, unsigned* __restrict__ counts,
                       unsigned* __restrict__ lossd) {
    int i = blockIdx.x * 256 + threadIdx.x;
    if (i < 131072) dw[i] = 0.f;
    int j = i - 131072;
    if (j >= 0 && j < 512) counts[j] = 0u;
    if (j >= 512 && j < 516) lossd[j - 512] = 0u;  // 2 doubles
}

// ---------------- dist GEMM: 2 waves/block, 128x64 per wave (R8-proven) ----------------
__global__ __launch_bounds__(128, 2) void k_dist(
    const ushort* __restrict__ xt, const ushort* __restrict__ eb,
    const float* __restrict__ se,
    float* __restrict__ partd, int* __restrict__ parti) {
    __shared__ ushort As[128 * 64];  // [row n][64 d] bf16, slot-swizzled
    __shared__ ushort Bs[128 * 64];  // [row k][64 d] bf16, slot-swizzled
    const int tid = threadIdx.x;
    const int lane = tid & 63, w = tid >> 6;  // w in {0,1}
    // XCD-aware swizzle: grid=2048 (%8==0, bijective)
    const int id = blockIdx.x;
    const int lin = (id & 7) * 256 + (id >> 3);
    const int bj = lin & 3, bi = lin >> 2;
    const int n0 = bi * 128, k0 = bj * 128;

    f32x4 acc[8][4] = {};

    for (int it = 0; it < 12; ++it) {
        const int region = it >> 2, sub = it & 3;
        const int aoff = (region == 2 ? 256 : 0) + sub * 64;  // x: hi,hi,lo
        const int boff = (region == 1 ? 256 : 0) + sub * 64;  // e: hi,lo,hi
#pragma unroll
        for (int i = 0; i < 8; ++i) {
            int r = i * 16 + w * 8 + (lane >> 3);
            int slot = (lane & 7) ^ (r & 7);
            const ushort* ga = xt + (size_t)(n0 + r) * 512 + aoff + slot * 8;
            const ushort* gb = eb + (size_t)(k0 + r) * 512 + boff + slot * 8;
            __builtin_amdgcn_global_load_lds(
                (const __attribute__((address_space(1))) void*)ga,
                (__attribute__((address_space(3))) void*)&As[(i * 16 + w * 8) * 64],
                16, 0, 0);
            __builtin_amdgcn_global_load_lds(
                (const __attribute__((address_space(1))) void*)gb,
                (__attribute__((address_space(3))) void*)&Bs[(i * 16 + w * 8) * 64],
                16, 0, 0);
        }
        __syncthreads();
#pragma unroll
        for (int kk = 0; kk < 2; ++kk) {
            bf16x8 af[8], bfr[4];
#pragma unroll
            for (int mi = 0; mi < 8; ++mi) {
                int row = mi * 16 + (lane & 15);
                int slot = (kk * 4 + (lane >> 4)) ^ (row & 7);
                af[mi] = *(const bf16x8*)&As[row * 64 + slot * 8];
            }
#pragma unroll
            for (int ni = 0; ni < 4; ++ni) {
                int row = w * 64 + ni * 16 + (lane & 15);
                int slot = (kk * 4 + (lane >> 4)) ^ (row & 7);
                bfr[ni] = *(const bf16x8*)&Bs[row * 64 + slot * 8];
            }
#pragma unroll
            for (int mi = 0; mi < 8; ++mi)
#pragma unroll
                for (int ni = 0; ni < 4; ++ni)
                    acc[mi][ni] = __builtin_amdgcn_mfma_f32_16x16x32_bf16(
                        af[mi], bfr[ni], acc[mi][ni], 0, 0, 0);
        }
        __syncthreads();
    }

    // epilogue: per-row argmin over this wave's 64 k, then cross-wave reduce
    float se4[4];
#pragma unroll
    for (int ni = 0; ni < 4; ++ni) se4[ni] = se[k0 + w * 64 + ni * 16 + (lane & 15)];
    float* pd = (float*)As;  // [128][32]
    int* pi = (int*)Bs;      // [128][32]
#pragma unroll
    for (int mi = 0; mi < 8; ++mi) {
#pragma unroll
        for (int j = 0; j < 4; ++j) {
            int r = mi * 16 + (lane >> 4) * 4 + j;
            float dmin = 3.4e38f;
            int bidx = 0x7fffffff;
#pragma unroll
            for (int ni = 0; ni < 4; ++ni) {
                int k = k0 + w * 64 + ni * 16 + (lane & 15);
                float dv = fmaf(-2.f, acc[mi][ni][j], se4[ni]);
                if (dv < dmin) { dmin = dv; bidx = k; }
            }
            pd[r * 32 + w * 16 + (lane & 15)] = dmin;
            pi[r * 32 + w * 16 + (lane & 15)] = bidx;
        }
    }
    __syncthreads();
    {
        float dmin = 3.4e38f;
        int bidx = 0x7fffffff;
        for (int c = 0; c < 32; ++c) {
            float dv = pd[tid * 32 + c];
            int iv = pi[tid * 32 + c];
            if (dv < dmin || (dv == dmin && iv < bidx)) { dmin = dv; bidx = iv; }
        }
        partd[(size_t)bj * N_TOT + n0 + tid] = dmin;
        parti[(size_t)bj * N_TOT + n0 + tid] = bidx;
    }
}

// ---------------- combine 4 k-tile partials -> idx (+ fused counts histogram) ----------------
__global__ void k_combine(const float* __restrict__ partd, const int* __restrict__ parti,
                          int* __restrict__ idx, unsigned* __restrict__ counts) {
    __shared__ unsigned h[512];
    int tid = threadIdx.x;
    h[tid] = 0u;
    h[tid + 256] = 0u;
    __syncthreads();
    int n = blockIdx.x * 256 + tid;
    float dmin = 3.4e38f;
    int bidx = 0x7fffffff;
#pragma unroll
    for (int p = 0; p < 4; ++p) {
        float dv = partd[(size_t)p * N_TOT + n];
        int iv = parti[(size_t)p * N_TOT + n];
        if (dv < dmin || (dv == dmin && iv < bidx)) { dmin = dv; bidx = iv; }
    }
    idx[n] = bidx;
    atomicAdd(&h[bidx], 1u);
    __syncthreads();
    if (h[tid]) atomicAdd(&counts[tid], h[tid]);
    if (h[tid + 256]) atomicAdd(&counts[tid + 256], h[tid + 256]);
}

// ---------------- enc zero + ones (R8-proven two-pass) ----------------
__global__ void k_enc_zero(float2* __restrict__ enc2) {
    size_t base = (size_t)blockIdx.x * (256 * 32) + threadIdx.x;
#pragma unroll
    for (int j = 0; j < 32; ++j) enc2[base + j * 256] = make_float2(0.f, 0.f);
}

__global__ void k_enc_ones(const int* __restrict__ idx, float* __restrict__ enc) {
    int n = blockIdx.x * 256 + threadIdx.x;
    enc[(size_t)n * KK + idx[n]] = 1.0f;
}

// ---------------- scalars: cluster-size norm + perplexity + offsets scan ----------------
__global__ void k_scalars(const unsigned* __restrict__ counts, const float* __restrict__ cs_in,
                          float* __restrict__ csn, float* __restrict__ pp_out,
                          unsigned* __restrict__ cursor) {
    __shared__ float red[512];
    __shared__ unsigned sc[512];
    int k = threadIdx.x;
    unsigned ci = counts[k];
    float c = (float)ci;
    float pre = cs_in[k] * 0.99f + 0.01f * c;
    red[k] = pre;
    sc[k] = ci;
    __syncthreads();
#pragma unroll
    for (int s = 256; s > 0; s >>= 1) {
        if (k < s) red[k] += red[k + s];
        __syncthreads();
    }
    float nsum = red[0];
    __syncthreads();
    csn[k] = (pre + 1e-5f) / (nsum + 512 * 1e-5f) * nsum;
    float p = c * (1.0f / 65536.f);
    red[k] = -p * logf(p + 1e-10f);
    __syncthreads();
#pragma unroll
    for (int s = 256; s > 0; s >>= 1) {
        if (k < s) red[k] += red[k + s];
        __syncthreads();
    }
    if (k == 0) pp_out[0] = expf(red[0]);
#pragma unroll
    for (int s = 1; s < 512; s <<= 1) {
        unsigned v = (k >= s) ? sc[k - s] : 0u;
        __syncthreads();
        sc[k] += v;
        __syncthreads();
    }
    cursor[k] = sc[k] - ci;
}

// ---------------- scatter packed (k<<17)|n into per-k buckets ----------------
__global__ void k_scatter(const int* __restrict__ idx, unsigned* __restrict__ cursor,
                          unsigned* __restrict__ sortedp) {
    int n = blockIdx.x * 256 + threadIdx.x;
    int k = idx[n];
    unsigned p = atomicAdd(&cursor[k], 1u);
    sortedp[p] = (unsigned)n | ((unsigned)k << 17);
}

// ---------------- dw: each wave sums a uniform 16-entry slice of sorted ----------------
__global__ __launch_bounds__(256) void k_dwsum(const ushort* __restrict__ xt,
                                               const unsigned* __restrict__ sortedp,
                                               float* __restrict__ dw) {
    int gw = blockIdx.x * 4 + (threadIdx.x >> 6);  // 0..4095
    int lane = threadIdx.x & 63;
    int base = gw * 16;
    unsigned pk[16];
#pragma unroll
    for (int i = 0; i < 16; ++i) pk[i] = sortedp[base + i];
    float acc[8] = {0.f, 0.f, 0.f, 0.f, 0.f, 0.f, 0.f, 0.f};
    int curk = (int)(pk[0] >> 17);
#pragma unroll
    for (int i = 0; i < 16; ++i) {
        int n = (int)(pk[i] & 0x1ffffu);
        int k = (int)(pk[i] >> 17);
        if (k != curk) {  // wave-uniform branch (slice is sorted)
#pragma unroll
            for (int j = 0; j < 8; ++j) {
                float other = __shfl(acc[j], lane + 32);
                if (lane < 32) atomicAdd(&dw[curk * DIM + lane * 8 + j], acc[j] + other);
                acc[j] = 0.f;
            }
            curk = k;
        }
        uint4 v = *(const uint4*)(xt + (size_t)n * 512 + lane * 8);
        unsigned u[4] = {v.x, v.y, v.z, v.w};
#pragma unroll
        for (int j = 0; j < 4; ++j) {
            acc[2 * j] += __uint_as_float(u[j] << 16);
            acc[2 * j + 1] += __uint_as_float(u[j] & 0xffff0000u);
        }
    }
#pragma unroll
    for (int j = 0; j < 8; ++j) {
        float other = __shfl(acc[j], lane + 32);
        if (lane < 32) atomicAdd(&dw[curk * DIM + lane * 8 + j], acc[j] + other);
    }
}

// ---------------- new embedding + fused loss term sum(c*ne^2 - 2*dw*ne) -> lossB ----------------
__global__ void k_newemb(const float* __restrict__ ema_w, const float* __restrict__ dw,
                         const float* __restrict__ csn, const unsigned* __restrict__ counts,
                         float* __restrict__ newemb, double* __restrict__ lossB) {
    int i = blockIdx.x * 256 + threadIdx.x;
    int k = i >> 8;
    float dwv = dw[i];
    float ne = (ema_w[i] * 0.99f + 0.01f * dwv) / csn[k];
    newemb[i] = ne;
    float c = (float)counts[k];
    float term = fmaf(c * ne, ne, -2.f * dwv * ne);
#pragma unroll
    for (int m = 1; m < 64; m <<= 1) term += __shfl_xor(term, m);
    if ((threadIdx.x & 63) == 0) atomicAdd(lossB, (double)term);
}

// ---------------- Q gather -> [B,D,T] output (pure gather+write; loss via identity) ----------------
__global__ __launch_bounds__(256) void k_out1(const int* __restrict__ idx,
                                              const float* __restrict__ newemb,
                                              float* __restrict__ out1) {
    __shared__ float q[256][68];
    int tid = threadIdx.x;
    int b = blockIdx.x >> 6, tc = blockIdx.x & 63;
    int tl = tid & 63, dg = tid >> 6;
    int kk = idx[b * TT + tc * 64 + tl];
    const float4* ne4 = (const float4*)(newemb + (size_t)kk * DIM);
#pragma unroll
    for (int d4 = 0; d4 < 16; ++d4) {
        float4 v = ne4[dg * 16 + d4];
        int d = dg * 64 + d4 * 4;
        q[d + 0][tl] = v.x;
        q[d + 1][tl] = v.y;
        q[d + 2][tl] = v.z;
        q[d + 3][tl] = v.w;
    }
    __syncthreads();
    float* ob = out1 + (size_t)b * DIM * TT + tc * 64;
#pragma unroll 8
    for (int j = 0; j < 64; ++j) {
        int fi = tid + 256 * j;
        int d = fi >> 6, t = fi & 63;
        ob[(size_t)d * TT + t] = q[d][t];
    }
}

// ---------------- finalize loss: 0.25 * (sum_x2 + sum(Q^2 - 2xQ)) / N ----------------
__global__ void k_loss_fin(const double* __restrict__ lossd, float* __restrict__ out0) {
    out0[0] = (float)(0.25 * (lossd[0] + lossd[1]) * (1.0 / 16777216.0));
}

extern "C" void kernel_launch(void* const* d_in, const int* in_sizes, int n_in,
                              void* d_out, int out_size, void* d_ws, size_t ws_size,
                              hipStream_t stream) {
    const float* in = (const float*)d_in[0];
    const float* emb = (const float*)d_in[1];
    const float* emaw = (const float*)d_in[2];
    const float* cs = (const float*)d_in[3];
    float* out = (float*)d_out;
    char* ws = (char*)d_ws;

    float* se = (float*)(ws + 0);                  // 512 f
    float* partd = (float*)(ws + 264192);          // 4*65536 f
    int* parti = (int*)(ws + 1312768);             // 4*65536 i
    int* idx = (int*)(ws + 2361344);               // 65536 i
    unsigned* counts = (unsigned*)(ws + 2623488);  // 512 u32
    float* csn = (float*)(ws + 2625536);           // 512 f
    float* dw = (float*)(ws + 2627584);            // 131072 f
    float* newemb = (float*)(ws + 3151872);        // 131072 f
    double* lossd = (double*)(ws + 3676160);       // 2 doubles (A=sum x^2, B=sum Q^2-2xQ)
    ushort* eb = (ushort*)(ws + 3676416);          // 512*512 bf16
    ushort* xt = (ushort*)(ws + 4200704);          // 65536*512 bf16 = 64 MB
    unsigned* sortedp = (unsigned*)(ws + 71309568); // 65536 u32
    unsigned* cursor = (unsigned*)(ws + 71573760);  // 512 u32

    float* out_loss = out;
    float* out_q = out + 1;
    float* out_pp = out + 16777217;
    float* enc = out + 16777218;

    hipLaunchKernelGGL(k_prep_e, dim3(512), dim3(64), 0, stream, emb, se, eb);
    hipLaunchKernelGGL(k_zero, dim3(515), dim3(256), 0, stream, dw, counts, (unsigned*)lossd);
    hipLaunchKernelGGL(k_split_x, dim3(4096), dim3(256), 0, stream, in, xt, lossd);
    hipLaunchKernelGGL(k_dist, dim3(2048), dim3(128), 0, stream, xt, eb, se, partd, parti);
    hipLaunchKernelGGL(k_combine, dim3(256), dim3(256), 0, stream, partd, parti, idx, counts);
    hipLaunchKernelGGL(k_enc_zero, dim3(2048), dim3(256), 0, stream, (float2*)enc);
    hipLaunchKernelGGL(k_enc_ones, dim3(256), dim3(256), 0, stream, idx, enc);
    hipLaunchKernelGGL(k_scalars, dim3(1), dim3(512), 0, stream, counts, cs, csn, out_pp, cursor);
    hipLaunchKernelGGL(k_scatter, dim3(256), dim3(256), 0, stream, idx, cursor, sortedp);
    hipLaunchKernelGGL(k_dwsum, dim3(1024), dim3(256), 0, stream, xt, sortedp, dw);
    hipLaunchKernelGGL(k_newemb, dim3(512), dim3(256), 0, stream, emaw, dw, csn, counts,
                       newemb, lossd + 1);
    hipLaunchKernelGGL(k_out1, dim3(1024), dim3(256), 0, stream, idx, newemb, out_q);
    hipLaunchKernelGGL(k_loss_fin, dim3(1), dim3(1), 0, stream, lossd, out_loss);
}

// Round 15
// 348.583 us; speedup vs baseline: 1.0753x; 1.0753x over previous
//
#include <hip/hip_runtime.h>

#define N_TOT 65536
#define DIM 256
#define KK 512
#define TT 4096
#define BB 16

typedef short bf16x8 __attribute__((ext_vector_type(8)));
typedef float f32x4 __attribute__((ext_vector_type(4)));

__device__ __forceinline__ ushort f2bf(float f) {
    unsigned u = __float_as_uint(f);
    unsigned r = (u + 0x7fffu + ((u >> 16) & 1u)) >> 16;
    return (ushort)r;
}

// ---------------- fused: se[k] + split emb -> eb[k][512] = [hi|lo] bf16 ----------------
__global__ void k_prep_e(const float* __restrict__ emb, float* __restrict__ se,
                         ushort* __restrict__ eb) {
    int k = blockIdx.x, tid = threadIdx.x;  // 64 threads
    int c0 = tid * 4;
    float4 v = *(const float4*)(emb + k * DIM + c0);
    float f[4] = {v.x, v.y, v.z, v.w};
    float s = f[0] * f[0] + f[1] * f[1] + f[2] * f[2] + f[3] * f[3];
#pragma unroll
    for (int m = 1; m < 64; m <<= 1) s += __shfl_xor(s, m);
    if (tid == 0) se[k] = s;
    ushort h[4], l[4];
#pragma unroll
    for (int j = 0; j < 4; ++j) {
        h[j] = f2bf(f[j]);
        float hf = __uint_as_float(((unsigned)h[j]) << 16);
        l[j] = f2bf(f[j] - hf);
    }
    uint2 hp = make_uint2((unsigned)h[0] | ((unsigned)h[1] << 16),
                          (unsigned)h[2] | ((unsigned)h[3] << 16));
    uint2 lp = make_uint2((unsigned)l[0] | ((unsigned)l[1] << 16),
                          (unsigned)l[2] | ((unsigned)l[3] << 16));
    *(uint2*)(eb + (size_t)k * 512 + c0) = hp;
    *(uint2*)(eb + (size_t)k * 512 + 256 + c0) = lp;
}

// ---------------- transpose + split x -> xt[n][512] = [hi(256) | lo(256)] bf16 ----------------
__global__ __launch_bounds__(256) void k_split_x(const float* __restrict__ in,
                                                 ushort* __restrict__ xt) {
    __shared__ float ls[64][65];
    int tid = threadIdx.x;
    int b = blockIdx.x >> 8;
    int rest = blockIdx.x & 255;
    int tt = rest >> 2, dt = rest & 3;
    int t0 = tt * 64, d0 = dt * 64;
    int tl = tid & 63, dg = tid >> 6;
    const float* src = in + (size_t)b * DIM * TT + t0 + tl;
#pragma unroll
    for (int p = 0; p < 16; ++p) {
        int d = dg * 16 + p;
        ls[d][tl] = src[(size_t)(d0 + d) * TT];
    }
    __syncthreads();
    int c0 = dg * 16;
    int n = b * TT + t0 + tl;
    ushort* row = xt + (size_t)n * 512;
    ushort h[16], l[16];
#pragma unroll
    for (int j = 0; j < 16; ++j) {
        float v = ls[c0 + j][tl];
        h[j] = f2bf(v);
        float hf = __uint_as_float(((unsigned)h[j]) << 16);
        l[j] = f2bf(v - hf);
    }
    uint hu[8], lu[8];
#pragma unroll
    for (int j = 0; j < 8; ++j) {
        hu[j] = (unsigned)h[2 * j] | ((unsigned)h[2 * j + 1] << 16);
        lu[j] = (unsigned)l[2 * j] | ((unsigned)l[2 * j + 1] << 16);
    }
    *(uint4*)(row + d0 + c0) = make_uint4(hu[0], hu[1], hu[2], hu[3]);
    *(uint4*)(row + d0 + c0 + 8) = make_uint4(hu[4], hu[5], hu[6], hu[7]);
    *(uint4*)(row + 256 + d0 + c0) = make_uint4(lu[0], lu[1], lu[2], lu[3]);
    *(uint4*)(row + 256 + d0 + c0 + 8) = make_uint4(lu[4], lu[5], lu[6], lu[7]);
}

// ---------------- zero dw / counts / loss accumulator ----------------
__global__ void k_zero(float* __restrict__ dw, unsigned* __restrict__ counts,
                       unsigned* __restrict__ lossd) {
    int i = blockIdx.x * 256 + threadIdx.x;
    if (i < 131072) dw[i] = 0.f;
    int j = i - 131072;
    if (j >= 0 && j < 512) counts[j] = 0u;
    if (j >= 512 && j < 514) lossd[j - 512] = 0u;
}

// ---------------- dist GEMM: 2 waves/block, 128x64 per wave (R8-proven) ----------------
__global__ __launch_bounds__(128, 2) void k_dist(
    const ushort* __restrict__ xt, const ushort* __restrict__ eb,
    const float* __restrict__ se,
    float* __restrict__ partd, int* __restrict__ parti) {
    __shared__ ushort As[128 * 64];  // [row n][64 d] bf16, slot-swizzled
    __shared__ ushort Bs[128 * 64];  // [row k][64 d] bf16, slot-swizzled
    const int tid = threadIdx.x;
    const int lane = tid & 63, w = tid >> 6;  // w in {0,1}
    // XCD-aware swizzle: grid=2048 (%8==0, bijective)
    const int id = blockIdx.x;
    const int lin = (id & 7) * 256 + (id >> 3);
    const int bj = lin & 3, bi = lin >> 2;
    const int n0 = bi * 128, k0 = bj * 128;

    f32x4 acc[8][4] = {};

    for (int it = 0; it < 12; ++it) {
        const int region = it >> 2, sub = it & 3;
        const int aoff = (region == 2 ? 256 : 0) + sub * 64;  // x: hi,hi,lo
        const int boff = (region == 1 ? 256 : 0) + sub * 64;  // e: hi,lo,hi
#pragma unroll
        for (int i = 0; i < 8; ++i) {
            int r = i * 16 + w * 8 + (lane >> 3);
            int slot = (lane & 7) ^ (r & 7);
            const ushort* ga = xt + (size_t)(n0 + r) * 512 + aoff + slot * 8;
            const ushort* gb = eb + (size_t)(k0 + r) * 512 + boff + slot * 8;
            __builtin_amdgcn_global_load_lds(
                (const __attribute__((address_space(1))) void*)ga,
                (__attribute__((address_space(3))) void*)&As[(i * 16 + w * 8) * 64],
                16, 0, 0);
            __builtin_amdgcn_global_load_lds(
                (const __attribute__((address_space(1))) void*)gb,
                (__attribute__((address_space(3))) void*)&Bs[(i * 16 + w * 8) * 64],
                16, 0, 0);
        }
        __syncthreads();
#pragma unroll
        for (int kk = 0; kk < 2; ++kk) {
            bf16x8 af[8], bfr[4];
#pragma unroll
            for (int mi = 0; mi < 8; ++mi) {
                int row = mi * 16 + (lane & 15);
                int slot = (kk * 4 + (lane >> 4)) ^ (row & 7);
                af[mi] = *(const bf16x8*)&As[row * 64 + slot * 8];
            }
#pragma unroll
            for (int ni = 0; ni < 4; ++ni) {
                int row = w * 64 + ni * 16 + (lane & 15);
                int slot = (kk * 4 + (lane >> 4)) ^ (row & 7);
                bfr[ni] = *(const bf16x8*)&Bs[row * 64 + slot * 8];
            }
#pragma unroll
            for (int mi = 0; mi < 8; ++mi)
#pragma unroll
                for (int ni = 0; ni < 4; ++ni)
                    acc[mi][ni] = __builtin_amdgcn_mfma_f32_16x16x32_bf16(
                        af[mi], bfr[ni], acc[mi][ni], 0, 0, 0);
        }
        __syncthreads();
    }

    // epilogue: per-row argmin over this wave's 64 k, then cross-wave reduce
    float se4[4];
#pragma unroll
    for (int ni = 0; ni < 4; ++ni) se4[ni] = se[k0 + w * 64 + ni * 16 + (lane & 15)];
    float* pd = (float*)As;  // [128][32]
    int* pi = (int*)Bs;      // [128][32]
#pragma unroll
    for (int mi = 0; mi < 8; ++mi) {
#pragma unroll
        for (int j = 0; j < 4; ++j) {
            int r = mi * 16 + (lane >> 4) * 4 + j;
            float dmin = 3.4e38f;
            int bidx = 0x7fffffff;
#pragma unroll
            for (int ni = 0; ni < 4; ++ni) {
                int k = k0 + w * 64 + ni * 16 + (lane & 15);
                float dv = fmaf(-2.f, acc[mi][ni][j], se4[ni]);
                if (dv < dmin) { dmin = dv; bidx = k; }
            }
            pd[r * 32 + w * 16 + (lane & 15)] = dmin;
            pi[r * 32 + w * 16 + (lane & 15)] = bidx;
        }
    }
    __syncthreads();
    {
        float dmin = 3.4e38f;
        int bidx = 0x7fffffff;
        for (int c = 0; c < 32; ++c) {
            float dv = pd[tid * 32 + c];
            int iv = pi[tid * 32 + c];
            if (dv < dmin || (dv == dmin && iv < bidx)) { dmin = dv; bidx = iv; }
        }
        partd[(size_t)bj * N_TOT + n0 + tid] = dmin;
        parti[(size_t)bj * N_TOT + n0 + tid] = bidx;
    }
}

// ---------------- combine 4 k-tile partials -> idx (+ fused counts histogram) ----------------
__global__ void k_combine(const float* __restrict__ partd, const int* __restrict__ parti,
                          int* __restrict__ idx, unsigned* __restrict__ counts) {
    __shared__ unsigned h[512];
    int tid = threadIdx.x;
    h[tid] = 0u;
    h[tid + 256] = 0u;
    __syncthreads();
    int n = blockIdx.x * 256 + tid;
    float dmin = 3.4e38f;
    int bidx = 0x7fffffff;
#pragma unroll
    for (int p = 0; p < 4; ++p) {
        float dv = partd[(size_t)p * N_TOT + n];
        int iv = parti[(size_t)p * N_TOT + n];
        if (dv < dmin || (dv == dmin && iv < bidx)) { dmin = dv; bidx = iv; }
    }
    idx[n] = bidx;
    atomicAdd(&h[bidx], 1u);
    __syncthreads();
    if (h[tid]) atomicAdd(&counts[tid], h[tid]);
    if (h[tid + 256]) atomicAdd(&counts[tid + 256], h[tid + 256]);
}

// ---------------- enc zero + ones (R8-proven two-pass) ----------------
__global__ void k_enc_zero(float2* __restrict__ enc2) {
    size_t base = (size_t)blockIdx.x * (256 * 32) + threadIdx.x;
#pragma unroll
    for (int j = 0; j < 32; ++j) enc2[base + j * 256] = make_float2(0.f, 0.f);
}

__global__ void k_enc_ones(const int* __restrict__ idx, float* __restrict__ enc) {
    int n = blockIdx.x * 256 + threadIdx.x;
    enc[(size_t)n * KK + idx[n]] = 1.0f;
}

// ---------------- scalars: cluster-size norm + perplexity + offsets scan ----------------
__global__ void k_scalars(const unsigned* __restrict__ counts, const float* __restrict__ cs_in,
                          float* __restrict__ csn, float* __restrict__ pp_out,
                          unsigned* __restrict__ cursor) {
    __shared__ float red[512];
    __shared__ unsigned sc[512];
    int k = threadIdx.x;
    unsigned ci = counts[k];
    float c = (float)ci;
    float pre = cs_in[k] * 0.99f + 0.01f * c;
    red[k] = pre;
    sc[k] = ci;
    __syncthreads();
#pragma unroll
    for (int s = 256; s > 0; s >>= 1) {
        if (k < s) red[k] += red[k + s];
        __syncthreads();
    }
    float nsum = red[0];
    __syncthreads();
    csn[k] = (pre + 1e-5f) / (nsum + 512 * 1e-5f) * nsum;
    float p = c * (1.0f / 65536.f);
    red[k] = -p * logf(p + 1e-10f);
    __syncthreads();
#pragma unroll
    for (int s = 256; s > 0; s >>= 1) {
        if (k < s) red[k] += red[k + s];
        __syncthreads();
    }
    if (k == 0) pp_out[0] = expf(red[0]);
#pragma unroll
    for (int s = 1; s < 512; s <<= 1) {
        unsigned v = (k >= s) ? sc[k - s] : 0u;
        __syncthreads();
        sc[k] += v;
        __syncthreads();
    }
    cursor[k] = sc[k] - ci;
}

// ---------------- scatter packed (k<<17)|n into per-k buckets ----------------
__global__ void k_scatter(const int* __restrict__ idx, unsigned* __restrict__ cursor,
                          unsigned* __restrict__ sortedp) {
    int n = blockIdx.x * 256 + threadIdx.x;
    int k = idx[n];
    unsigned p = atomicAdd(&cursor[k], 1u);
    sortedp[p] = (unsigned)n | ((unsigned)k << 17);
}

// ---------------- dw: each wave sums a uniform 16-entry slice of sorted ----------------
__global__ __launch_bounds__(256) void k_dwsum(const ushort* __restrict__ xt,
                                               const unsigned* __restrict__ sortedp,
                                               float* __restrict__ dw) {
    int gw = blockIdx.x * 4 + (threadIdx.x >> 6);  // 0..4095
    int lane = threadIdx.x & 63;
    int base = gw * 16;
    unsigned pk[16];
#pragma unroll
    for (int i = 0; i < 16; ++i) pk[i] = sortedp[base + i];
    float acc[8] = {0.f, 0.f, 0.f, 0.f, 0.f, 0.f, 0.f, 0.f};
    int curk = (int)(pk[0] >> 17);
#pragma unroll
    for (int i = 0; i < 16; ++i) {
        int n = (int)(pk[i] & 0x1ffffu);
        int k = (int)(pk[i] >> 17);
        if (k != curk) {  // wave-uniform branch (slice is sorted)
#pragma unroll
            for (int j = 0; j < 8; ++j) {
                float other = __shfl(acc[j], lane + 32);
                if (lane < 32) atomicAdd(&dw[curk * DIM + lane * 8 + j], acc[j] + other);
                acc[j] = 0.f;
            }
            curk = k;
        }
        uint4 v = *(const uint4*)(xt + (size_t)n * 512 + lane * 8);
        unsigned u[4] = {v.x, v.y, v.z, v.w};
#pragma unroll
        for (int j = 0; j < 4; ++j) {
            acc[2 * j] += __uint_as_float(u[j] << 16);
            acc[2 * j + 1] += __uint_as_float(u[j] & 0xffff0000u);
        }
    }
#pragma unroll
    for (int j = 0; j < 8; ++j) {
        float other = __shfl(acc[j], lane + 32);
        if (lane < 32) atomicAdd(&dw[curk * DIM + lane * 8 + j], acc[j] + other);
    }
}

// ---------------- new embedding ----------------
__global__ void k_newemb(const float* __restrict__ ema_w, const float* __restrict__ dw,
                         const float* __restrict__ csn, float* __restrict__ newemb) {
    int i = blockIdx.x * 256 + threadIdx.x;
    int k = i >> 8;
    newemb[i] = (ema_w[i] * 0.99f + 0.01f * dw[i]) / csn[k];
}

// ---------------- Q gather -> [B,D,T] output + latent loss (R8-proven fused) ----------------
__global__ __launch_bounds__(256) void k_out1(const float* __restrict__ in,
                                              const int* __restrict__ idx,
                                              const float* __restrict__ newemb,
                                              float* __restrict__ out1,
                                              unsigned long long* __restrict__ lossd) {
    __shared__ float q[256][68];
    __shared__ float redl[4];
    int tid = threadIdx.x;
    int b = blockIdx.x >> 6, tc = blockIdx.x & 63;
    int tl = tid & 63, dg = tid >> 6;
    int kk = idx[b * TT + tc * 64 + tl];
    const float4* ne4 = (const float4*)(newemb + (size_t)kk * DIM);
#pragma unroll
    for (int d4 = 0; d4 < 16; ++d4) {
        float4 v = ne4[dg * 16 + d4];
        int d = dg * 64 + d4 * 4;
        q[d + 0][tl] = v.x;
        q[d + 1][tl] = v.y;
        q[d + 2][tl] = v.z;
        q[d + 3][tl] = v.w;
    }
    __syncthreads();
    float lacc = 0.f;
    const float* xb = in + (size_t)b * DIM * TT + tc * 64;
    float* ob = out1 + (size_t)b * DIM * TT + tc * 64;
#pragma unroll 4
    for (int j = 0; j < 64; ++j) {
        int fi = tid + 256 * j;
        int d = fi >> 6, t = fi & 63;
        float qv = q[d][t];
        float xv = xb[(size_t)d * TT + t];
        ob[(size_t)d * TT + t] = qv;
        float df = qv - xv;
        lacc = fmaf(df, df, lacc);
    }
#pragma unroll
    for (int m = 1; m < 64; m <<= 1) lacc += __shfl_xor(lacc, m);
    if ((tid & 63) == 0) redl[tid >> 6] = lacc;
    __syncthreads();
    if (tid == 0) {
        double s = (double)redl[0] + (double)redl[1] + (double)redl[2] + (double)redl[3];
        atomicAdd((double*)lossd, s);
    }
}

// ---------------- finalize loss ----------------
__global__ void k_loss_fin(const double* __restrict__ lossd, float* __restrict__ out0) {
    out0[0] = (float)(0.25 * lossd[0] * (1.0 / 16777216.0));
}

extern "C" void kernel_launch(void* const* d_in, const int* in_sizes, int n_in,
                              void* d_out, int out_size, void* d_ws, size_t ws_size,
                              hipStream_t stream) {
    const float* in = (const float*)d_in[0];
    const float* emb = (const float*)d_in[1];
    const float* emaw = (const float*)d_in[2];
    const float* cs = (const float*)d_in[3];
    float* out = (float*)d_out;
    char* ws = (char*)d_ws;

    float* se = (float*)(ws + 0);                  // 512 f
    float* partd = (float*)(ws + 264192);          // 4*65536 f
    int* parti = (int*)(ws + 1312768);             // 4*65536 i
    int* idx = (int*)(ws + 2361344);               // 65536 i
    unsigned* counts = (unsigned*)(ws + 2623488);  // 512 u32
    float* csn = (float*)(ws + 2625536);           // 512 f
    float* dw = (float*)(ws + 2627584);            // 131072 f
    float* newemb = (float*)(ws + 3151872);        // 131072 f
    double* lossd = (double*)(ws + 3676160);       // 1 double
    ushort* eb = (ushort*)(ws + 3676416);          // 512*512 bf16
    ushort* xt = (ushort*)(ws + 4200704);          // 65536*512 bf16 = 64 MB
    unsigned* sortedp = (unsigned*)(ws + 71309568); // 65536 u32
    unsigned* cursor = (unsigned*)(ws + 71573760);  // 512 u32

    float* out_loss = out;
    float* out_q = out + 1;
    float* out_pp = out + 16777217;
    float* enc = out + 16777218;

    hipLaunchKernelGGL(k_prep_e, dim3(512), dim3(64), 0, stream, emb, se, eb);
    hipLaunchKernelGGL(k_split_x, dim3(4096), dim3(256), 0, stream, in, xt);
    hipLaunchKernelGGL(k_zero, dim3(515), dim3(256), 0, stream, dw, counts, (unsigned*)lossd);
    hipLaunchKernelGGL(k_dist, dim3(2048), dim3(128), 0, stream, xt, eb, se, partd, parti);
    hipLaunchKernelGGL(k_combine, dim3(256), dim3(256), 0, stream, partd, parti, idx, counts);
    hipLaunchKernelGGL(k_enc_zero, dim3(2048), dim3(256), 0, stream, (float2*)enc);
    hipLaunchKernelGGL(k_enc_ones, dim3(256), dim3(256), 0, stream, idx, enc);
    hipLaunchKernelGGL(k_scalars, dim3(1), dim3(512), 0, stream, counts, cs, csn, out_pp, cursor);
    hipLaunchKernelGGL(k_scatter, dim3(256), dim3(256), 0, stream, idx, cursor, sortedp);
    hipLaunchKernelGGL(k_dwsum, dim3(1024), dim3(256), 0, stream, xt, sortedp, dw);
    hipLaunchKernelGGL(k_newemb, dim3(512), dim3(256), 0, stream, emaw, dw, csn, newemb);
    hipLaunchKernelGGL(k_out1, dim3(1024), dim3(256), 0, stream, in, idx, newemb, out_q,
                       (unsigned long long*)lossd);
    hipLaunchKernelGGL(k_loss_fin, dim3(1), dim3(1), 0, stream, lossd, out_loss);
}